// Round 8
// baseline (209.601 us; speedup 1.0000x reference)
//
#include <hip/hip_runtime.h>
#include <string.h>

// GAT layer on MI355X. N=50000, E=800000 (+N self loops), DIN=256, DOUT=128, H=8.
//
//  memset       : bcount[196] = 0   (hipMemsetAsync, graph-capture legal)
//  K1 gemm_bp   : [blocks 0..1562]  gemm: h_bf = bf16(x @ W^T), 16x16x32 MFMA,
//                 16 prefetched x-float4s/lane, B-frags converted from fp32 W
//                 inline (W is L2-hot), 16 rows x 64 cols per wave
//                 [blocks 1563..]   bucket_pass: edges -> per-256-node-bucket
//                 regions (atomic cursors, packed u32 = src<<8 | dst&255),
//                 CHUNK=4096 (measured best r6)
//  K2 ns_fs     : [blocks 0..1562]  node_scores: a_src/a_dst from h_bf
//                 [blocks 1563..]   fine_scatter: one block per bucket, per-dst
//                 LDS hist+scan -> offsets[], self-loop inject, flat ushort CSR
//  K3 aggregate : one wave per dst node, flat CSR, 4 edges per wave-instr
//                 (16 lanes x uint4 per edge)

constexpr int DIN  = 256;
constexpr int DOUT = 128;
constexpr int H    = 8;
constexpr int CAP  = 5120;   // pair_buf slots per bucket (mean 4096, +16 sigma)
constexpr int CHUNK = 4096;  // edges per bucket_pass block

typedef __attribute__((ext_vector_type(8))) short bf16x8;
typedef __attribute__((ext_vector_type(4))) float f32x4;

__device__ __forceinline__ float lrelu(float s) { return s >= 0.0f ? s : 0.2f * s; }

__device__ __forceinline__ unsigned short f2bf(float f) {  // RNE
  unsigned u = __float_as_uint(f);
  u += 0x7FFF + ((u >> 16) & 1);
  return (unsigned short)(u >> 16);
}
__device__ __forceinline__ float bflo(unsigned u) { return __uint_as_float(u << 16); }
__device__ __forceinline__ float bfhi(unsigned u) { return __uint_as_float(u & 0xFFFF0000u); }

__device__ __forceinline__ int wave_incl_scan(int v, int lane) {
#pragma unroll
  for (int d = 1; d < 64; d <<= 1) {
    int t = __shfl_up(v, d, 64);
    if (lane >= d) v += t;
  }
  return v;
}

__device__ __forceinline__ bf16x8 pack8(const float4& lo, const float4& hi) {
  bf16x8 a;
  a[0] = (short)f2bf(lo.x); a[1] = (short)f2bf(lo.y);
  a[2] = (short)f2bf(lo.z); a[3] = (short)f2bf(lo.w);
  a[4] = (short)f2bf(hi.x); a[5] = (short)f2bf(hi.y);
  a[6] = (short)f2bf(hi.z); a[7] = (short)f2bf(hi.w);
  return a;
}

// ---------------- K1: fused GEMM + bucket_pass ----------------
// gemm wave: 16 rows x 64 cols. A-frag lane(mr,kg) holds A[m0+mr][ks*32+kg*8..+8);
// B-frag from fp32 W inline; C/D: col = lane&15, row = kg*4 + reg.
__global__ __launch_bounds__(256) void gemm_bp(const float* __restrict__ x,
                                               const float* __restrict__ W,
                                               unsigned short* __restrict__ hbf, int N,
                                               const int* __restrict__ ei,
                                               int* __restrict__ bcount,
                                               unsigned* __restrict__ pair_buf,
                                               int E, int nb, int gemm_blocks) {
  __shared__ int hist[256];
  __shared__ int gbase[256];
  if ((int)blockIdx.x >= gemm_blocks) {
    // ---- bucket_pass (4096 edges per block) ----
    int c0 = (blockIdx.x - gemm_blocks) * CHUNK;
    hist[threadIdx.x] = 0;
    __syncthreads();
    int dcache[16];
#pragma unroll
    for (int q = 0; q < 16; ++q) {
      int e = c0 + q * 256 + threadIdx.x;
      dcache[q] = (e < E) ? ei[E + e] : -1;
      if (dcache[q] >= 0) atomicAdd(&hist[dcache[q] >> 8], 1);
    }
    __syncthreads();
    if (threadIdx.x < nb) {
      int c = hist[threadIdx.x];
      gbase[threadIdx.x] = c ? atomicAdd(&bcount[threadIdx.x], c) : 0;
    }
    __syncthreads();
    hist[threadIdx.x] = 0;  // reuse as local rank cursor
    __syncthreads();
#pragma unroll
    for (int q = 0; q < 16; ++q) {
      int e = c0 + q * 256 + threadIdx.x;
      if (dcache[q] >= 0) {
        int s = ei[e];
        int bk = dcache[q] >> 8;
        int r = atomicAdd(&hist[bk], 1);
        pair_buf[bk * CAP + gbase[bk] + r] = ((unsigned)s << 8) | (unsigned)(dcache[q] & 255);
      }
    }
    return;
  }
  // ---- GEMM ----
  int gb = blockIdx.x;
  int tid = threadIdx.x;
  int w = tid >> 6, lane = tid & 63;
  int mr = lane & 15, kg = lane >> 4;
  int m0 = gb * 32 + (w >> 1) * 16;
  int nt0 = (w & 1) * 4;  // first of 4 n-tiles (cols nt0*16 .. nt0*16+63)
  if (m0 >= N) return;
  int rr = m0 + mr;
  if (rr >= N) rr = N - 1;  // clamp (stores are guarded; dup reads harmless)
  const float* xrow = x + (size_t)rr * DIN + kg * 8;

  // prefetch all 16 x-vectors (16 outstanding loads/lane)
  float4 xa[8], xc[8];
#pragma unroll
  for (int ks = 0; ks < 8; ++ks) {
    xa[ks] = *(const float4*)(xrow + ks * 32);
    xc[ks] = *(const float4*)(xrow + ks * 32 + 4);
  }

  f32x4 acc[4];
#pragma unroll
  for (int t = 0; t < 4; ++t) acc[t] = (f32x4){0.f, 0.f, 0.f, 0.f};

#pragma unroll
  for (int ks = 0; ks < 8; ++ks) {
    bf16x8 a = pack8(xa[ks], xc[ks]);
#pragma unroll
    for (int t = 0; t < 4; ++t) {
      const float* wp = W + ((nt0 + t) * 16 + mr) * DIN + ks * 32 + kg * 8;
      float4 blo = *(const float4*)wp;
      float4 bhi = *(const float4*)(wp + 4);
      bf16x8 b = pack8(blo, bhi);
      acc[t] = __builtin_amdgcn_mfma_f32_16x16x32_bf16(a, b, acc[t], 0, 0, 0);
    }
  }
#pragma unroll
  for (int t = 0; t < 4; ++t) {
#pragma unroll
    for (int r = 0; r < 4; ++r) {
      int row = m0 + kg * 4 + r;
      if (row < N) hbf[row * DOUT + (nt0 + t) * 16 + mr] = f2bf(acc[t][r]);
    }
  }
}

// ---------------- K2: fused node_scores + fine_scatter ----------------
__global__ __launch_bounds__(256) void ns_fs(const unsigned* __restrict__ pair_buf,
                                             const int* __restrict__ bcount,
                                             int* __restrict__ offsets,
                                             unsigned short* __restrict__ src_sorted,
                                             const unsigned short* __restrict__ hbf,
                                             const float* __restrict__ Wa,
                                             float* __restrict__ a_src,
                                             float* __restrict__ a_dst,
                                             int N, int E, int nb, int ns_blocks) {
  __shared__ int cnt[256];
  __shared__ int cur[256];
  __shared__ int redS[256];
  __shared__ int wsumS[4];
  const int t = threadIdx.x;
  if ((int)blockIdx.x < ns_blocks) {
    // ---- node_scores ----
    int idx = (int)blockIdx.x * 256 + t;
    if (idx >= N * H) return;
    int v = idx >> 3, hh = idx & 7;
    const unsigned short* hp = hbf + (size_t)v * DOUT + hh * 16;
    uint4 p0 = *(const uint4*)hp;
    uint4 p1 = *(const uint4*)(hp + 8);
    float hv[16];
    hv[0] = bflo(p0.x); hv[1] = bfhi(p0.x); hv[2] = bflo(p0.y); hv[3] = bfhi(p0.y);
    hv[4] = bflo(p0.z); hv[5] = bfhi(p0.z); hv[6] = bflo(p0.w); hv[7] = bfhi(p0.w);
    hv[8] = bflo(p1.x); hv[9] = bfhi(p1.x); hv[10] = bflo(p1.y); hv[11] = bfhi(p1.y);
    hv[12] = bflo(p1.z); hv[13] = bfhi(p1.z); hv[14] = bflo(p1.w); hv[15] = bfhi(p1.w);
    float s1 = 0.f, s2 = 0.f;
#pragma unroll
    for (int d = 0; d < 16; ++d) {
      s1 += hv[d] * Wa[d];
      s2 += hv[d] * Wa[16 + d];
    }
    a_src[idx] = s1;
    a_dst[idx] = s2;
    return;
  }
  // ---- fine_scatter: one block per bucket (256 nodes) ----
  const int B = blockIdx.x - ns_blocks;
  const int node0 = B * 256;
  const int v = node0 + t;
  const int valid = (v < N);
  cnt[t] = valid ? 1 : 0;  // self loop
  __syncthreads();
  const int cntE = bcount[B];
  const unsigned* reg = pair_buf + B * CAP;
  for (int i = t; i < cntE; i += 256)
    atomicAdd(&cnt[reg[i] & 255], 1);
  // bucket edge base = sum of earlier bucket counts
  redS[t] = (t < B) ? bcount[t] : 0;
  __syncthreads();
  for (int s = 128; s > 0; s >>= 1) {
    if (t < s) redS[t] += redS[t + s];
    __syncthreads();
  }
  const int csr_base = redS[0] + node0;  // edges + self loops before this bucket
  int val = cnt[t];
  int lane = t & 63, wv = t >> 6;
  int inc = wave_incl_scan(val, lane);
  if (lane == 63) wsumS[wv] = inc;
  __syncthreads();
  int base = 0;
  for (int q = 0; q < wv; ++q) base += wsumS[q];
  int ex = base + inc - val;
  cur[t] = ex + 1;  // slot 0 = self loop
  if (valid) {
    offsets[v] = csr_base + ex;
    src_sorted[csr_base + ex] = (unsigned short)v;  // self loop
  }
  if (B == 0 && t == 0) offsets[N] = E + N;
  __syncthreads();
  for (int i = t; i < cntE; i += 256) {
    unsigned p = reg[i];
    int k = atomicAdd(&cur[p & 255], 1);
    src_sorted[csr_base + k] = (unsigned short)(p >> 8);
  }
}

// ---------------- K3: aggregation, flat CSR, 4 edges / wave-instr ----------------
// One wave per dst node. Group g = lane>>4 handles edge j+g; sub-lane sl = lane&15
// covers cols [sl*8, sl*8+8) (16B uint4 load); head = sl>>1.
__global__ __launch_bounds__(256) void aggregate(const unsigned short* __restrict__ hbf,
                                                 const float* __restrict__ a_src,
                                                 const float* __restrict__ a_dst,
                                                 const float* __restrict__ b_att,
                                                 const int* __restrict__ offsets,
                                                 const unsigned short* __restrict__ src_sorted,
                                                 float* __restrict__ out, int N) {
  int wid = blockIdx.x * 4 + (threadIdx.x >> 6);
  if (wid >= N) return;
  int lane = threadIdx.x & 63;
  int g = lane >> 4, sl = lane & 15;
  int head = sl >> 1;
  float adv = a_dst[wid * H + head] + b_att[0];
  int beg = offsets[wid], end = offsets[wid + 1];
  float a0 = 0, a1 = 0, a2 = 0, a3 = 0, a4 = 0, a5 = 0, a6 = 0, a7 = 0, den = 0;
  for (int j0 = beg; j0 < end; j0 += 4) {
    int jj = j0 + g;
    bool valid = jj < end;
    int jc = valid ? jj : beg;  // beg always exists (self loop)
    int s = src_sorted[jc];
    float as = a_src[s * H + head];
    uint4 u = *(const uint4*)(hbf + s * DOUT + sl * 8);
    float e = valid ? __expf(lrelu(as + adv)) : 0.f;
    den += e;
    a0 += e * bflo(u.x); a1 += e * bfhi(u.x);
    a2 += e * bflo(u.y); a3 += e * bfhi(u.y);
    a4 += e * bflo(u.z); a5 += e * bfhi(u.z);
    a6 += e * bflo(u.w); a7 += e * bfhi(u.w);
  }
  den += __shfl_xor(den, 16, 64); den += __shfl_xor(den, 32, 64);
  a0 += __shfl_xor(a0, 16, 64); a0 += __shfl_xor(a0, 32, 64);
  a1 += __shfl_xor(a1, 16, 64); a1 += __shfl_xor(a1, 32, 64);
  a2 += __shfl_xor(a2, 16, 64); a2 += __shfl_xor(a2, 32, 64);
  a3 += __shfl_xor(a3, 16, 64); a3 += __shfl_xor(a3, 32, 64);
  a4 += __shfl_xor(a4, 16, 64); a4 += __shfl_xor(a4, 32, 64);
  a5 += __shfl_xor(a5, 16, 64); a5 += __shfl_xor(a5, 32, 64);
  a6 += __shfl_xor(a6, 16, 64); a6 += __shfl_xor(a6, 32, 64);
  a7 += __shfl_xor(a7, 16, 64); a7 += __shfl_xor(a7, 32, 64);
  float inv = 1.0f / den;
  if (g == 0) {
    float4 o = make_float4(a0 * inv, a1 * inv, a2 * inv, a3 * inv);
    *(float4*)&out[wid * DOUT + sl * 8] = o;
  } else if (g == 1) {
    float4 o = make_float4(a4 * inv, a5 * inv, a6 * inv, a7 * inv);
    *(float4*)&out[wid * DOUT + sl * 8 + 4] = o;
  }
}

extern "C" void kernel_launch(void* const* d_in, const int* in_sizes, int n_in,
                              void* d_out, int out_size, void* d_ws, size_t ws_size,
                              hipStream_t stream) {
  const float* x     = (const float*)d_in[0];
  const float* W     = (const float*)d_in[1];
  const float* Wa    = (const float*)d_in[2];
  const float* b_att = (const float*)d_in[3];
  const int*   ei    = (const int*)d_in[4];
  const int N  = in_sizes[0] / DIN;
  const int E  = in_sizes[4] / 2;
  const int NB = (N + 255) / 256;  // 196 buckets
  float* out = (float*)d_out;

  char* p = (char*)d_ws;
  auto take = [&p](size_t bytes) {
    uintptr_t u = ((uintptr_t)p + 15) & ~(uintptr_t)15;
    p = (char*)(u + bytes);
    return (void*)u;
  };
  unsigned short* hbf = (unsigned short*)take((size_t)N * DOUT * 2);
  float* a_src        = (float*)take((size_t)N * H * 4);
  float* a_dst        = (float*)take((size_t)N * H * 4);
  int* bcount         = (int*)take((size_t)NB * 4);
  unsigned* pair_buf  = (unsigned*)take((size_t)NB * CAP * 4);
  int* offsets        = (int*)take((size_t)(N + 1) * 4);
  unsigned short* src_sorted = (unsigned short*)take((size_t)(E + N + 16) * 2);

  dim3 b256(256);
  const int gemm_blocks = (N + 31) / 32;            // 1563
  const int bp_blocks   = (E + CHUNK - 1) / CHUNK;  // 196
  const int ns_blocks   = (N * H + 255) / 256;      // 1563

  hipMemsetAsync(bcount, 0, (size_t)NB * 4, stream);
  gemm_bp<<<dim3(gemm_blocks + bp_blocks), b256, 0, stream>>>(
      x, W, hbf, N, ei, bcount, pair_buf, E, NB, gemm_blocks);
  ns_fs<<<dim3(ns_blocks + NB), b256, 0, stream>>>(
      pair_buf, bcount, offsets, src_sorted, hbf, Wa, a_src, a_dst, N, E, NB, ns_blocks);
  aggregate<<<dim3((N + 3) / 4), b256, 0, stream>>>(hbf, a_src, a_dst, b_att, offsets,
                                                    src_sorted, out, N);
}

// Round 9
// 185.015 us; speedup vs baseline: 1.1329x; 1.1329x over previous
//
#include <hip/hip_runtime.h>

// GAT layer on MI355X. N=50000, E=800000 (+N self loops), DIN=256, DOUT=128, H=8.
//
//  K1 conv_w     : W_bf = bf16(W_trans); zeroes per-bucket counters
//  K2 bp_gemm    : [blocks 0..195]  bucket_pass: edges -> per-256-node-bucket
//                  regions (atomic cursors, packed u32 = src<<8 | dst&255),
//                  CHUNK=4096 (measured best r6)
//                  [blocks 196..]   gemm: h_bf = bf16(x @ W^T), 16x16x32 MFMA,
//                  one wave = 16 rows x 128 cols (r4 shape, measured 44.8us)
//  K3 fs_ns      : [blocks 0..195]  fine_scatter: one block per bucket, per-dst
//                  LDS hist+scan -> offsets[], self-loop inject, flat ushort CSR
//                  [blocks 196..]   node_scores: a_src/a_dst from h_bf
//  K4 aggregate  : one wave per dst node, flat CSR, 8 edges per loop iter
//                  (2 per 16-lane group -> two gather chains in flight)

constexpr int DIN  = 256;
constexpr int DOUT = 128;
constexpr int H    = 8;
constexpr int CAP  = 5120;   // pair_buf slots per bucket (mean 4096, +16 sigma)
constexpr int CHUNK = 4096;  // edges per bucket_pass block (measured best)

typedef __attribute__((ext_vector_type(8))) short bf16x8;
typedef __attribute__((ext_vector_type(4))) float f32x4;

__device__ __forceinline__ float lrelu(float s) { return s >= 0.0f ? s : 0.2f * s; }

__device__ __forceinline__ unsigned short f2bf(float f) {  // RNE
  unsigned u = __float_as_uint(f);
  u += 0x7FFF + ((u >> 16) & 1);
  return (unsigned short)(u >> 16);
}
__device__ __forceinline__ float bflo(unsigned u) { return __uint_as_float(u << 16); }
__device__ __forceinline__ float bfhi(unsigned u) { return __uint_as_float(u & 0xFFFF0000u); }

__device__ __forceinline__ int wave_incl_scan(int v, int lane) {
#pragma unroll
  for (int d = 1; d < 64; d <<= 1) {
    int t = __shfl_up(v, d, 64);
    if (lane >= d) v += t;
  }
  return v;
}

// ---------------- K1: W -> bf16 (+ zero bucket counters) ----------------
__global__ void conv_w(const float* __restrict__ W, unsigned short* __restrict__ Wbf,
                       int n, int* __restrict__ bcount, int nb) {
  int i = blockIdx.x * blockDim.x + threadIdx.x;
  if (i < n) Wbf[i] = f2bf(W[i]);
  if (blockIdx.x == 0 && threadIdx.x < nb) bcount[threadIdx.x] = 0;
}

// ---------------- K2: fused bucket_pass + GEMM ----------------
// gemm wave: 16 rows x 128 cols (8 n-tiles). A-frag lane(mr,kg) holds
// A[m0+mr][ks*32+kg*8..+8); C/D: col = lane&15, row = kg*4 + reg.
__global__ __launch_bounds__(256) void bp_gemm(const float* __restrict__ x,
                                               const unsigned short* __restrict__ Wbf,
                                               unsigned short* __restrict__ hbf, int N,
                                               const int* __restrict__ ei,
                                               int* __restrict__ bcount,
                                               unsigned* __restrict__ pair_buf,
                                               int E, int nb, int bp_blocks) {
  __shared__ int hist[256];
  __shared__ int gbase[256];
  if ((int)blockIdx.x < bp_blocks) {
    // ---- bucket_pass (4096 edges per block) ----
    int c0 = blockIdx.x * CHUNK;
    hist[threadIdx.x] = 0;
    __syncthreads();
    int dcache[16];
#pragma unroll
    for (int q = 0; q < 16; ++q) {
      int e = c0 + q * 256 + threadIdx.x;
      dcache[q] = (e < E) ? ei[E + e] : -1;
      if (dcache[q] >= 0) atomicAdd(&hist[dcache[q] >> 8], 1);
    }
    __syncthreads();
    if (threadIdx.x < nb) {
      int c = hist[threadIdx.x];
      gbase[threadIdx.x] = c ? atomicAdd(&bcount[threadIdx.x], c) : 0;
    }
    __syncthreads();
    hist[threadIdx.x] = 0;  // reuse as local rank cursor
    __syncthreads();
#pragma unroll
    for (int q = 0; q < 16; ++q) {
      int e = c0 + q * 256 + threadIdx.x;
      if (dcache[q] >= 0) {
        int s = ei[e];
        int bk = dcache[q] >> 8;
        int r = atomicAdd(&hist[bk], 1);
        pair_buf[bk * CAP + gbase[bk] + r] = ((unsigned)s << 8) | (unsigned)(dcache[q] & 255);
      }
    }
    return;
  }
  // ---- GEMM (r4 shape: one wave per 16 rows, all 128 cols) ----
  int wid = (blockIdx.x - bp_blocks) * 4 + (threadIdx.x >> 6);
  int m0 = wid * 16;
  if (m0 >= N) return;
  int lane = threadIdx.x & 63;
  int mr = lane & 15;
  int kg = lane >> 4;
  int rr = m0 + mr;
  if (rr >= N) rr = N - 1;  // clamp (stores guarded; dup reads harmless)
  const float* xrow = x + (size_t)rr * DIN + kg * 8;

  f32x4 acc[8];
#pragma unroll
  for (int t = 0; t < 8; ++t) acc[t] = (f32x4){0.f, 0.f, 0.f, 0.f};

#pragma unroll
  for (int ks = 0; ks < 8; ++ks) {
    float4 alo = *(const float4*)(xrow + ks * 32);
    float4 ahi = *(const float4*)(xrow + ks * 32 + 4);
    bf16x8 a;
    a[0] = (short)f2bf(alo.x); a[1] = (short)f2bf(alo.y);
    a[2] = (short)f2bf(alo.z); a[3] = (short)f2bf(alo.w);
    a[4] = (short)f2bf(ahi.x); a[5] = (short)f2bf(ahi.y);
    a[6] = (short)f2bf(ahi.z); a[7] = (short)f2bf(ahi.w);
#pragma unroll
    for (int t = 0; t < 8; ++t) {
      bf16x8 b = *(const bf16x8*)(Wbf + ((size_t)(t * 16 + mr) * DIN + ks * 32 + kg * 8));
      acc[t] = __builtin_amdgcn_mfma_f32_16x16x32_bf16(a, b, acc[t], 0, 0, 0);
    }
  }
#pragma unroll
  for (int t = 0; t < 8; ++t) {
#pragma unroll
    for (int r = 0; r < 4; ++r) {
      int row = m0 + kg * 4 + r;
      if (row < N) hbf[(size_t)row * DOUT + t * 16 + mr] = f2bf(acc[t][r]);
    }
  }
}

// ---------------- K3: fused fine_scatter + node_scores ----------------
__global__ __launch_bounds__(256) void fs_ns(const unsigned* __restrict__ pair_buf,
                                             const int* __restrict__ bcount,
                                             int* __restrict__ offsets,
                                             unsigned short* __restrict__ src_sorted,
                                             const unsigned short* __restrict__ hbf,
                                             const float* __restrict__ Wa,
                                             float* __restrict__ a_src,
                                             float* __restrict__ a_dst,
                                             int N, int E, int nb) {
  __shared__ int cnt[256];
  __shared__ int cur[256];
  __shared__ int redS[256];
  __shared__ int wsumS[4];
  const int t = threadIdx.x;
  if ((int)blockIdx.x >= nb) {
    // ---- node_scores ----
    int idx = ((int)blockIdx.x - nb) * 256 + t;
    if (idx >= N * H) return;
    int v = idx >> 3, hh = idx & 7;
    const unsigned short* hp = hbf + (size_t)v * DOUT + hh * 16;
    uint4 p0 = *(const uint4*)hp;
    uint4 p1 = *(const uint4*)(hp + 8);
    float hv[16];
    hv[0] = bflo(p0.x); hv[1] = bfhi(p0.x); hv[2] = bflo(p0.y); hv[3] = bfhi(p0.y);
    hv[4] = bflo(p0.z); hv[5] = bfhi(p0.z); hv[6] = bflo(p0.w); hv[7] = bfhi(p0.w);
    hv[8] = bflo(p1.x); hv[9] = bfhi(p1.x); hv[10] = bflo(p1.y); hv[11] = bfhi(p1.y);
    hv[12] = bflo(p1.z); hv[13] = bfhi(p1.z); hv[14] = bflo(p1.w); hv[15] = bfhi(p1.w);
    float s1 = 0.f, s2 = 0.f;
#pragma unroll
    for (int d = 0; d < 16; ++d) {
      s1 += hv[d] * Wa[d];
      s2 += hv[d] * Wa[16 + d];
    }
    a_src[idx] = s1;
    a_dst[idx] = s2;
    return;
  }
  // ---- fine_scatter: one block per bucket (256 nodes) ----
  const int B = blockIdx.x;
  const int node0 = B * 256;
  const int v = node0 + t;
  const int valid = (v < N);
  cnt[t] = valid ? 1 : 0;  // self loop
  __syncthreads();
  const int cntE = bcount[B];
  const unsigned* reg = pair_buf + B * CAP;
  for (int i = t; i < cntE; i += 256)
    atomicAdd(&cnt[reg[i] & 255], 1);
  // bucket edge base = sum of earlier bucket counts
  redS[t] = (t < B) ? bcount[t] : 0;
  __syncthreads();
  for (int s = 128; s > 0; s >>= 1) {
    if (t < s) redS[t] += redS[t + s];
    __syncthreads();
  }
  const int csr_base = redS[0] + node0;  // edges + self loops before this bucket
  int val = cnt[t];
  int lane = t & 63, wv = t >> 6;
  int inc = wave_incl_scan(val, lane);
  if (lane == 63) wsumS[wv] = inc;
  __syncthreads();
  int base = 0;
  for (int q = 0; q < wv; ++q) base += wsumS[q];
  int ex = base + inc - val;
  cur[t] = ex + 1;  // slot 0 = self loop
  if (valid) {
    offsets[v] = csr_base + ex;
    src_sorted[csr_base + ex] = (unsigned short)v;  // self loop
  }
  if (B == 0 && t == 0) offsets[N] = E + N;
  __syncthreads();
  for (int i = t; i < cntE; i += 256) {
    unsigned p = reg[i];
    int k = atomicAdd(&cur[p & 255], 1);
    src_sorted[csr_base + k] = (unsigned short)(p >> 8);
  }
}

// ---------------- K4: aggregation, flat CSR, 8 edges per iter ----------------
// One wave per dst node. Group g = lane>>4 handles edges j0+g and j0+4+g
// (two independent gather chains in flight); sub-lane sl = lane&15 covers
// cols [sl*8, sl*8+8) (16B uint4 load); head = sl>>1.
__global__ __launch_bounds__(256) void aggregate(const unsigned short* __restrict__ hbf,
                                                 const float* __restrict__ a_src,
                                                 const float* __restrict__ a_dst,
                                                 const float* __restrict__ b_att,
                                                 const int* __restrict__ offsets,
                                                 const unsigned short* __restrict__ src_sorted,
                                                 float* __restrict__ out, int N) {
  int wid = blockIdx.x * 4 + (threadIdx.x >> 6);
  if (wid >= N) return;
  int lane = threadIdx.x & 63;
  int g = lane >> 4, sl = lane & 15;
  int head = sl >> 1;
  float adv = a_dst[wid * H + head] + b_att[0];
  int beg = offsets[wid], end = offsets[wid + 1];
  float a0 = 0, a1 = 0, a2 = 0, a3 = 0, a4 = 0, a5 = 0, a6 = 0, a7 = 0, den = 0;
  for (int j0 = beg; j0 < end; j0 += 8) {
    int ja = j0 + g, jb = j0 + 4 + g;
    bool va = ja < end, vb = jb < end;
    int sa = src_sorted[va ? ja : beg];
    int sb = src_sorted[vb ? jb : beg];
    float asa = a_src[sa * H + head];
    float asb = a_src[sb * H + head];
    uint4 ua = *(const uint4*)(hbf + sa * DOUT + sl * 8);
    uint4 ub = *(const uint4*)(hbf + sb * DOUT + sl * 8);
    float ea = va ? __expf(lrelu(asa + adv)) : 0.f;
    float eb = vb ? __expf(lrelu(asb + adv)) : 0.f;
    den += ea + eb;
    a0 += ea * bflo(ua.x) + eb * bflo(ub.x);
    a1 += ea * bfhi(ua.x) + eb * bfhi(ub.x);
    a2 += ea * bflo(ua.y) + eb * bflo(ub.y);
    a3 += ea * bfhi(ua.y) + eb * bfhi(ub.y);
    a4 += ea * bflo(ua.z) + eb * bflo(ub.z);
    a5 += ea * bfhi(ua.z) + eb * bfhi(ub.z);
    a6 += ea * bflo(ua.w) + eb * bflo(ub.w);
    a7 += ea * bfhi(ua.w) + eb * bfhi(ub.w);
  }
  den += __shfl_xor(den, 16, 64); den += __shfl_xor(den, 32, 64);
  a0 += __shfl_xor(a0, 16, 64); a0 += __shfl_xor(a0, 32, 64);
  a1 += __shfl_xor(a1, 16, 64); a1 += __shfl_xor(a1, 32, 64);
  a2 += __shfl_xor(a2, 16, 64); a2 += __shfl_xor(a2, 32, 64);
  a3 += __shfl_xor(a3, 16, 64); a3 += __shfl_xor(a3, 32, 64);
  a4 += __shfl_xor(a4, 16, 64); a4 += __shfl_xor(a4, 32, 64);
  a5 += __shfl_xor(a5, 16, 64); a5 += __shfl_xor(a5, 32, 64);
  a6 += __shfl_xor(a6, 16, 64); a6 += __shfl_xor(a6, 32, 64);
  a7 += __shfl_xor(a7, 16, 64); a7 += __shfl_xor(a7, 32, 64);
  float inv = 1.0f / den;
  if (g == 0) {
    float4 o = make_float4(a0 * inv, a1 * inv, a2 * inv, a3 * inv);
    *(float4*)&out[wid * DOUT + sl * 8] = o;
  } else if (g == 1) {
    float4 o = make_float4(a4 * inv, a5 * inv, a6 * inv, a7 * inv);
    *(float4*)&out[wid * DOUT + sl * 8 + 4] = o;
  }
}

extern "C" void kernel_launch(void* const* d_in, const int* in_sizes, int n_in,
                              void* d_out, int out_size, void* d_ws, size_t ws_size,
                              hipStream_t stream) {
  const float* x     = (const float*)d_in[0];
  const float* W     = (const float*)d_in[1];
  const float* Wa    = (const float*)d_in[2];
  const float* b_att = (const float*)d_in[3];
  const int*   ei    = (const int*)d_in[4];
  const int N  = in_sizes[0] / DIN;
  const int E  = in_sizes[4] / 2;
  const int NB = (N + 255) / 256;  // 196 buckets
  float* out = (float*)d_out;

  char* p = (char*)d_ws;
  auto take = [&p](size_t bytes) {
    uintptr_t u = ((uintptr_t)p + 15) & ~(uintptr_t)15;
    p = (char*)(u + bytes);
    return (void*)u;
  };
  unsigned short* hbf = (unsigned short*)take((size_t)N * DOUT * 2);
  unsigned short* Wbf = (unsigned short*)take((size_t)DOUT * DIN * 2);
  float* a_src        = (float*)take((size_t)N * H * 4);
  float* a_dst        = (float*)take((size_t)N * H * 4);
  int* bcount         = (int*)take((size_t)NB * 4);
  unsigned* pair_buf  = (unsigned*)take((size_t)NB * CAP * 4);
  int* offsets        = (int*)take((size_t)(N + 1) * 4);
  unsigned short* src_sorted = (unsigned short*)take((size_t)(E + N + 16) * 2);

  dim3 b256(256);
  const int bp_blocks   = (E + CHUNK - 1) / CHUNK;   // 196
  const int gemm_blocks = ((N + 15) / 16 + 3) / 4;   // 782 (4 waves x 16 rows each)
  const int ns_blocks   = (N * H + 255) / 256;       // 1563

  conv_w<<<dim3((DOUT * DIN + 255) / 256), b256, 0, stream>>>(W, Wbf, DOUT * DIN, bcount, NB);
  bp_gemm<<<dim3(bp_blocks + gemm_blocks), b256, 0, stream>>>(
      x, Wbf, hbf, N, ei, bcount, pair_buf, E, NB, bp_blocks);
  fs_ns<<<dim3(NB + ns_blocks), b256, 0, stream>>>(
      pair_buf, bcount, offsets, src_sorted, hbf, Wa, a_src, a_dst, N, E, NB);
  aggregate<<<dim3((N + 3) / 4), b256, 0, stream>>>(hbf, a_src, a_dst, b_att, offsets,
                                                    src_sorted, out, N);
}